// Round 2
// baseline (1149.167 us; speedup 1.0000x reference)
//
#include <hip/hip_runtime.h>
#include <stdint.h>

typedef unsigned short u16;
typedef unsigned int u32;
typedef __bf16 bf16x8 __attribute__((ext_vector_type(8)));
typedef float f32x4 __attribute__((ext_vector_type(4)));
typedef float f32x16 __attribute__((ext_vector_type(16)));
typedef u16 u16x4 __attribute__((ext_vector_type(4)));
typedef u16 u16x8 __attribute__((ext_vector_type(8)));

#define MFMA16(a, b, c) __builtin_amdgcn_mfma_f32_16x16x32_bf16(a, b, c, 0, 0, 0)
#define MFMA32(a, b, c) __builtin_amdgcn_mfma_f32_32x32x16_bf16(a, b, c, 0, 0, 0)

__device__ __forceinline__ u16 f2bf(float f) {
  u32 u = __builtin_bit_cast(u32, f);
  u += 0x7FFFu + ((u >> 16) & 1u);
  return (u16)(u >> 16);
}

__device__ __forceinline__ bf16x8 ld16(const u16* p) {
  return __builtin_bit_cast(bf16x8, *(const uint4*)p);
}

// ---------------- weight conversion (once per launch) ----------------
__global__ __launch_bounds__(256) void convert_weights(
    const float* __restrict__ Wq, const float* __restrict__ Wk,
    const float* __restrict__ Wv, const float* __restrict__ fcw,
    u16* __restrict__ wq_b, u16* __restrict__ wk_b, u16* __restrict__ wv_b,
    u16* __restrict__ fcw_b) {
  int bx = blockIdx.x, tid = threadIdx.x;
  if (bx < 4096) {
    int i = (bx * 256 + tid) * 4;
    float4 f = *(const float4*)&fcw[i];
    u16x4 o = {f2bf(f.x), f2bf(f.y), f2bf(f.z), f2bf(f.w)};
    *(u16x4*)&fcw_b[i] = o;
  } else {
    int i = ((bx - 4096) * 256 + tid) * 4;
    const float sc = 0.022097086912079612f;  // 1/sqrt(2048) folded into Wq
    float4 q = *(const float4*)&Wq[i];
    u16x4 oq = {f2bf(q.x * sc), f2bf(q.y * sc), f2bf(q.z * sc), f2bf(q.w * sc)};
    *(u16x4*)&wq_b[i] = oq;
    float4 k = *(const float4*)&Wk[i];
    u16x4 ok = {f2bf(k.x), f2bf(k.y), f2bf(k.z), f2bf(k.w)};
    *(u16x4*)&wk_b[i] = ok;
    float4 v = *(const float4*)&Wv[i];
    u16x4 ov = {f2bf(v.x), f2bf(v.y), f2bf(v.z), f2bf(v.w)};
    *(u16x4*)&wv_b[i] = ov;
  }
}

// ---------------- QKV projection with gather ----------------
__global__ __launch_bounds__(384) void qkv_kernel(
    const float* __restrict__ src, const u16* __restrict__ wq,
    const u16* __restrict__ wk, const u16* __restrict__ wvw,
    u16* __restrict__ Q, u16* __restrict__ K, u16* __restrict__ Vt, int bsh) {
  __shared__ u16 X[64 * 136];
  int jt = blockIdx.x, h = blockIdx.y, n = blockIdx.z;
  int tid = threadIdx.x;
  int i0 = h >> 1, c0 = (h & 1) * 128;
  for (int it = 0; it < 3; ++it) {
    int c = tid + it * 384;
    if (c < 1024) {
      int row = c >> 4, seg = c & 15;
      int j = jt * 64 + row;
      int pos = (8 * j + i0 - bsh) & 4095;
      const float* g = src + ((size_t)n * 4096 + pos) * 256 + c0 + seg * 8;
      float4 f0 = *(const float4*)g;
      float4 f1 = *(const float4*)(g + 4);
      u16x8 v = {f2bf(f0.x), f2bf(f0.y), f2bf(f0.z), f2bf(f0.w),
                 f2bf(f1.x), f2bf(f1.y), f2bf(f1.z), f2bf(f1.w)};
      *(u16x8*)&X[row * 136 + seg * 8] = v;
    }
  }
  __syncthreads();
  int wv = tid >> 6, ln = tid & 63;
  int mat = wv >> 1;
  int cbase = (wv & 1) * 64;
  const u16* W = (mat == 0) ? wq : (mat == 1) ? wk : wvw;
  int lr = ln & 15, lg = ln >> 4;
  f32x4 acc[4][4] = {};
#pragma unroll
  for (int kt = 0; kt < 4; ++kt) {
    bf16x8 a[4], b[4];
#pragma unroll
    for (int mt = 0; mt < 4; ++mt)
      a[mt] = ld16(&X[(mt * 16 + lr) * 136 + kt * 32 + lg * 8]);
#pragma unroll
    for (int nc = 0; nc < 4; ++nc)
      b[nc] = ld16(&W[(cbase + nc * 16 + lr) * 128 + kt * 32 + lg * 8]);
#pragma unroll
    for (int mt = 0; mt < 4; ++mt)
#pragma unroll
      for (int nc = 0; nc < 4; ++nc)
        acc[mt][nc] = MFMA16(a[mt], b[nc], acc[mt][nc]);
  }
  size_t nh = (size_t)(n * 16 + h);
  if (mat < 2) {
    u16* dst = (mat == 0 ? Q : K) + nh * 512 * 128;
#pragma unroll
    for (int mt = 0; mt < 4; ++mt)
#pragma unroll
      for (int nc = 0; nc < 4; ++nc) {
        int col = cbase + nc * 16 + lr;
        int jb = jt * 64 + mt * 16 + lg * 4;
#pragma unroll
        for (int r = 0; r < 4; ++r)
          dst[(size_t)(jb + r) * 128 + col] = f2bf(acc[mt][nc][r]);
      }
  } else {
    u16* dst = Vt + nh * 128 * 512;
#pragma unroll
    for (int mt = 0; mt < 4; ++mt)
#pragma unroll
      for (int nc = 0; nc < 4; ++nc) {
        int col = cbase + nc * 16 + lr;
        int jb = jt * 64 + mt * 16 + lg * 4;
        u16x4 pk = {f2bf(acc[mt][nc][0]), f2bf(acc[mt][nc][1]),
                    f2bf(acc[mt][nc][2]), f2bf(acc[mt][nc][3])};
        *(u16x4*)&dst[(size_t)col * 512 + jb] = pk;
      }
  }
}

// ---------------- flash attention, no LDS / no barriers ----------------
// Grid: (qt=4, h=16, n=8), 256 threads (4 waves); wave owns 32 q-rows.
// Swapped QK^T (mfma(K,Q)): lane holds S[q=lane&31][k], 32 vals/lane.
// P->A-frag in-register via v_cvt_pk_bf16_f32 + v_permlane32_swap_b32.
__global__ __launch_bounds__(256, 2) void attn_kernel(
    const u16* __restrict__ Q, const u16* __restrict__ K,
    const u16* __restrict__ Vt, u16* __restrict__ O) {
  int qt = blockIdx.x, h = blockIdx.y, n = blockIdx.z;
  int tid = threadIdx.x, wv = tid >> 6, ln = tid & 63;
  int l31 = ln & 31, hh = ln >> 5;
  size_t nh = (size_t)(n * 16 + h);
  int q0 = qt * 128 + wv * 32;
  const u16* Qb = Q + ((size_t)nh * 512 + q0) * 128;
  const u16* Kb = K + (size_t)nh * 512 * 128;
  const u16* Vb = Vt + (size_t)nh * 128 * 512;
  bf16x8 qf[8];
#pragma unroll
  for (int kt = 0; kt < 8; ++kt)
    qf[kt] = ld16(&Qb[l31 * 128 + kt * 16 + hh * 8]);
  f32x16 o[4] = {};  // D[q][d]: col=l31=d (d=nb*32+l31), row q=(r&3)+8*(r>>2)+4*hh
  float m = -1e30f, l = 0.f;

  for (int kv = 0; kv < 8; ++kv) {
    const u16* kp = Kb + (size_t)kv * 64 * 128;
    // S^T = K Q^T : lane holds S[q=l31][k = 32*kb + (r&3)+8*(r>>2)+4*hh]
    f32x16 s[2] = {};
#pragma unroll
    for (int kb = 0; kb < 2; ++kb)
#pragma unroll
      for (int kt = 0; kt < 8; ++kt) {
        bf16x8 a = ld16(&kp[(size_t)(kb * 32 + l31) * 128 + kt * 16 + hh * 8]);
        s[kb] = MFMA32(a, qf[kt], s[kb]);
      }
    // row max: in-lane tree + one cross-half shfl
    float mx[8];
#pragma unroll
    for (int i = 0; i < 8; ++i)
      mx[i] = fmaxf(fmaxf(s[0][2 * i], s[0][2 * i + 1]),
                    fmaxf(s[1][2 * i], s[1][2 * i + 1]));
    float pm = fmaxf(fmaxf(fmaxf(mx[0], mx[1]), fmaxf(mx[2], mx[3])),
                     fmaxf(fmaxf(mx[4], mx[5]), fmaxf(mx[6], mx[7])));
    pm = fmaxf(pm, __shfl_xor(pm, 32));
    // defer-max: only rescale when the running max grows by >8
    if (!__all(pm <= m + 8.f)) {
      float nm = fmaxf(m, pm);
      float al = __expf(m - nm);
      l *= al;
      m = nm;
#pragma unroll
      for (int r = 0; r < 16; ++r) {
        int qr = (r & 3) + 8 * (r >> 2) + 4 * hh;
        float av = __shfl(al, (ln & 32) | qr, 64);
        o[0][r] *= av; o[1][r] *= av; o[2][r] *= av; o[3][r] *= av;
      }
    }
    // exp + row sum
#pragma unroll
    for (int kb = 0; kb < 2; ++kb)
#pragma unroll
      for (int r = 0; r < 16; ++r) s[kb][r] = __expf(s[kb][r] - m);
    float sm[8];
#pragma unroll
    for (int i = 0; i < 8; ++i)
      sm[i] = (s[0][2 * i] + s[0][2 * i + 1]) + (s[1][2 * i] + s[1][2 * i + 1]);
    float rs = ((sm[0] + sm[1]) + (sm[2] + sm[3])) +
               ((sm[4] + sm[5]) + (sm[6] + sm[7]));
    rs += __shfl_xor(rs, 32);
    l += rs;
    // P -> PV A-frags fully in-register (cvt_pk + permlane32_swap)
    bf16x8 pa[4];
#pragma unroll
    for (int ks = 0; ks < 4; ++ks) {
      const int kb = ks >> 1, r0 = 8 * (ks & 1);
      u32 wA, wB, wC, wD;
      asm("v_cvt_pk_bf16_f32 %0, %1, %2" : "=v"(wA) : "v"(s[kb][r0 + 0]), "v"(s[kb][r0 + 1]));
      asm("v_cvt_pk_bf16_f32 %0, %1, %2" : "=v"(wB) : "v"(s[kb][r0 + 2]), "v"(s[kb][r0 + 3]));
      asm("v_cvt_pk_bf16_f32 %0, %1, %2" : "=v"(wC) : "v"(s[kb][r0 + 4]), "v"(s[kb][r0 + 5]));
      asm("v_cvt_pk_bf16_f32 %0, %1, %2" : "=v"(wD) : "v"(s[kb][r0 + 6]), "v"(s[kb][r0 + 7]));
      asm("v_permlane32_swap_b32 %0, %1" : "+v"(wA), "+v"(wC));
      asm("v_permlane32_swap_b32 %0, %1" : "+v"(wB), "+v"(wD));
      uint4 ww = {wA, wB, wC, wD};
      pa[ks] = __builtin_bit_cast(bf16x8, ww);
    }
    // O += P V  (V read direct from global: B[k][d] = Vt[d][k])
#pragma unroll
    for (int ks = 0; ks < 4; ++ks)
#pragma unroll
      for (int nb = 0; nb < 4; ++nb) {
        bf16x8 bv = ld16(&Vb[(size_t)(nb * 32 + l31) * 512 + kv * 64 + ks * 16 + hh * 8]);
        o[nb] = MFMA32(pa[ks], bv, o[nb]);
      }
  }
  // normalize + write attn_out [n*512+q][2048]
  float inv = 1.f / l;
#pragma unroll
  for (int r = 0; r < 16; ++r) {
    int qr = (r & 3) + 8 * (r >> 2) + 4 * hh;
    float iv = __shfl(inv, (ln & 32) | qr, 64);
    int row = q0 + qr;
    u16* dst = O + ((size_t)n * 512 + row) * 2048 + h * 128;
    dst[0 * 32 + l31] = f2bf(o[0][r] * iv);
    dst[1 * 32 + l31] = f2bf(o[1][r] * iv);
    dst[2 * 32 + l31] = f2bf(o[2][r] * iv);
    dst[3 * 32 + l31] = f2bf(o[3][r] * iv);
  }
}

// ---------------- FC GEMM + bias + permuted scatter ----------------
__global__ __launch_bounds__(256) void fc_kernel(
    const u16* __restrict__ A, const u16* __restrict__ Bw,
    const float* __restrict__ bias, float* __restrict__ dout, int bsh) {
  __shared__ u16 Al[128 * 32];
  __shared__ u16 Bl[128 * 32];
  int bn = blockIdx.x, bm = blockIdx.y;
  int tid = threadIdx.x, wv = tid >> 6, ln = tid & 63;
  int lr = ln & 15, lg = ln >> 4;
  int R0 = bm * 128, C0 = bn * 128;
  int wr = (wv & 1) * 64, wc = (wv >> 1) * 64;
  int lrow = ln >> 2, lseg = ln & 3;
  f32x4 acc[4][4] = {};
  for (int ks = 0; ks < 64; ++ks) {
    int k0 = ks * 32;
#pragma unroll
    for (int ch = wv; ch < 8; ch += 4) {
      const u16* ga = A + (size_t)(R0 + ch * 16 + lrow) * 2048 + k0 + lseg * 8;
      __builtin_amdgcn_global_load_lds(
          (const __attribute__((address_space(1))) u32*)ga,
          (__attribute__((address_space(3))) u32*)&Al[ch * 512], 16, 0, 0);
      const u16* gb = Bw + (size_t)(C0 + ch * 16 + lrow) * 2048 + k0 + lseg * 8;
      __builtin_amdgcn_global_load_lds(
          (const __attribute__((address_space(1))) u32*)gb,
          (__attribute__((address_space(3))) u32*)&Bl[ch * 512], 16, 0, 0);
    }
    __syncthreads();
    bf16x8 a[4], b[4];
#pragma unroll
    for (int mt = 0; mt < 4; ++mt)
      a[mt] = ld16(&Al[(wr + mt * 16 + lr) * 32 + lg * 8]);
#pragma unroll
    for (int nc = 0; nc < 4; ++nc)
      b[nc] = ld16(&Bl[(wc + nc * 16 + lr) * 32 + lg * 8]);
#pragma unroll
    for (int mt = 0; mt < 4; ++mt)
#pragma unroll
      for (int nc = 0; nc < 4; ++nc)
        acc[mt][nc] = MFMA16(a[mt], b[nc], acc[mt][nc]);
    __syncthreads();
  }
#pragma unroll
  for (int nc = 0; nc < 4; ++nc) {
    int e = C0 + wc + nc * 16 + lr;
    float bv = bias[e];
    int i = e >> 8, cc = e & 255;
#pragma unroll
    for (int mt = 0; mt < 4; ++mt)
#pragma unroll
      for (int r = 0; r < 4; ++r) {
        int row = R0 + wr + mt * 16 + lg * 4 + r;
        int nn = row >> 9, j = row & 511;
        int pos = (8 * j + i - bsh) & 4095;
        dout[((size_t)nn * 4096 + pos) * 256 + cc] = acc[mt][nc][r] + bv;
      }
  }
}

extern "C" void kernel_launch(void* const* d_in, const int* in_sizes, int n_in,
                              void* d_out, int out_size, void* d_ws, size_t ws_size,
                              hipStream_t stream) {
  const float* M = (const float*)d_in[0];
  const float* Wq = (const float*)d_in[1];
  const float* Wk = (const float*)d_in[2];
  const float* Wv = (const float*)d_in[3];
  const float* fcw = (const float*)d_in[4];
  const float* fcb = (const float*)d_in[5];
  float* out = (float*)d_out;
  char* ws = (char*)d_ws;
  u16* wq_b = (u16*)(ws + (0 << 10));
  u16* wk_b = (u16*)(ws + (32 << 10));
  u16* wv_b = (u16*)(ws + (64 << 10));
  u16* fcw_b = (u16*)(ws + (128 << 10));
  u16* Qb = (u16*)(ws + ((size_t)16 << 20));
  u16* Kb = (u16*)(ws + ((size_t)32 << 20));
  u16* Vtb = (u16*)(ws + ((size_t)48 << 20));
  u16* Ab = (u16*)(ws + ((size_t)64 << 20));

  convert_weights<<<4112, 256, 0, stream>>>(Wq, Wk, Wv, fcw, wq_b, wk_b, wv_b, fcw_b);
  for (int b = 0; b < 8; ++b) {
    const float* src = (b == 0) ? M : out;
    qkv_kernel<<<dim3(8, 16, 8), 384, 0, stream>>>(src, wq_b, wk_b, wv_b, Qb, Kb, Vtb, b);
    attn_kernel<<<dim3(4, 16, 8), 256, 0, stream>>>(Qb, Kb, Vtb, Ab);
    fc_kernel<<<dim3(16, 32), 256, 0, stream>>>(Ab, fcw_b, fcb, out, b);
  }
}

// Round 3
// 809.951 us; speedup vs baseline: 1.4188x; 1.4188x over previous
//
#include <hip/hip_runtime.h>
#include <stdint.h>

typedef unsigned short u16;
typedef unsigned int u32;
typedef __bf16 bf16x8 __attribute__((ext_vector_type(8)));
typedef float f32x4 __attribute__((ext_vector_type(4)));
typedef float f32x16 __attribute__((ext_vector_type(16)));
typedef u16 u16x4 __attribute__((ext_vector_type(4)));
typedef u16 u16x8 __attribute__((ext_vector_type(8)));

#define MFMA16(a, b, c) __builtin_amdgcn_mfma_f32_16x16x32_bf16(a, b, c, 0, 0, 0)
#define MFMA32(a, b, c) __builtin_amdgcn_mfma_f32_32x32x16_bf16(a, b, c, 0, 0, 0)

__device__ __forceinline__ u16 f2bf(float f) {
  u32 u = __builtin_bit_cast(u32, f);
  u += 0x7FFFu + ((u >> 16) & 1u);
  return (u16)(u >> 16);
}

__device__ __forceinline__ bf16x8 ld16(const u16* p) {
  return __builtin_bit_cast(bf16x8, *(const uint4*)p);
}

__device__ __forceinline__ void gl_lds(const u16* src, u16* lds) {
  __builtin_amdgcn_global_load_lds(
      (const __attribute__((address_space(1))) u32*)src,
      (__attribute__((address_space(3))) u32*)lds, 16, 0, 0);
}

// ---------------- weight conversion (once per launch) ----------------
__global__ __launch_bounds__(256) void convert_weights(
    const float* __restrict__ Wq, const float* __restrict__ Wk,
    const float* __restrict__ Wv, const float* __restrict__ fcw,
    u16* __restrict__ wq_b, u16* __restrict__ wk_b, u16* __restrict__ wv_b,
    u16* __restrict__ fcw_b) {
  int bx = blockIdx.x, tid = threadIdx.x;
  if (bx < 4096) {
    int i = (bx * 256 + tid) * 4;
    float4 f = *(const float4*)&fcw[i];
    u16x4 o = {f2bf(f.x), f2bf(f.y), f2bf(f.z), f2bf(f.w)};
    *(u16x4*)&fcw_b[i] = o;
  } else {
    int i = ((bx - 4096) * 256 + tid) * 4;
    const float sc = 0.022097086912079612f;  // 1/sqrt(2048) folded into Wq
    float4 q = *(const float4*)&Wq[i];
    u16x4 oq = {f2bf(q.x * sc), f2bf(q.y * sc), f2bf(q.z * sc), f2bf(q.w * sc)};
    *(u16x4*)&wq_b[i] = oq;
    float4 k = *(const float4*)&Wk[i];
    u16x4 ok = {f2bf(k.x), f2bf(k.y), f2bf(k.z), f2bf(k.w)};
    *(u16x4*)&wk_b[i] = ok;
    float4 v = *(const float4*)&Wv[i];
    u16x4 ov = {f2bf(v.x), f2bf(v.y), f2bf(v.z), f2bf(v.w)};
    *(u16x4*)&wv_b[i] = ov;
  }
}

// ---------------- QKV projection with gather ----------------
__global__ __launch_bounds__(384) void qkv_kernel(
    const float* __restrict__ src, const u16* __restrict__ wq,
    const u16* __restrict__ wk, const u16* __restrict__ wvw,
    u16* __restrict__ Q, u16* __restrict__ K, u16* __restrict__ Vt, int bsh) {
  __shared__ u16 X[64 * 136];
  int jt = blockIdx.x, h = blockIdx.y, n = blockIdx.z;
  int tid = threadIdx.x;
  int i0 = h >> 1, c0 = (h & 1) * 128;
  for (int it = 0; it < 3; ++it) {
    int c = tid + it * 384;
    if (c < 1024) {
      int row = c >> 4, seg = c & 15;
      int j = jt * 64 + row;
      int pos = (8 * j + i0 - bsh) & 4095;
      const float* g = src + ((size_t)n * 4096 + pos) * 256 + c0 + seg * 8;
      float4 f0 = *(const float4*)g;
      float4 f1 = *(const float4*)(g + 4);
      u16x8 v = {f2bf(f0.x), f2bf(f0.y), f2bf(f0.z), f2bf(f0.w),
                 f2bf(f1.x), f2bf(f1.y), f2bf(f1.z), f2bf(f1.w)};
      *(u16x8*)&X[row * 136 + seg * 8] = v;
    }
  }
  __syncthreads();
  int wv = tid >> 6, ln = tid & 63;
  int mat = wv >> 1;
  int cbase = (wv & 1) * 64;
  const u16* W = (mat == 0) ? wq : (mat == 1) ? wk : wvw;
  int lr = ln & 15, lg = ln >> 4;
  f32x4 acc[4][4] = {};
#pragma unroll
  for (int kt = 0; kt < 4; ++kt) {
    bf16x8 a[4], b[4];
#pragma unroll
    for (int mt = 0; mt < 4; ++mt)
      a[mt] = ld16(&X[(mt * 16 + lr) * 136 + kt * 32 + lg * 8]);
#pragma unroll
    for (int nc = 0; nc < 4; ++nc)
      b[nc] = ld16(&W[(cbase + nc * 16 + lr) * 128 + kt * 32 + lg * 8]);
#pragma unroll
    for (int mt = 0; mt < 4; ++mt)
#pragma unroll
      for (int nc = 0; nc < 4; ++nc)
        acc[mt][nc] = MFMA16(a[mt], b[nc], acc[mt][nc]);
  }
  size_t nh = (size_t)(n * 16 + h);
  if (mat < 2) {
    u16* dst = (mat == 0 ? Q : K) + nh * 512 * 128;
#pragma unroll
    for (int mt = 0; mt < 4; ++mt)
#pragma unroll
      for (int nc = 0; nc < 4; ++nc) {
        int col = cbase + nc * 16 + lr;
        int jb = jt * 64 + mt * 16 + lg * 4;
#pragma unroll
        for (int r = 0; r < 4; ++r)
          dst[(size_t)(jb + r) * 128 + col] = f2bf(acc[mt][nc][r]);
      }
  } else {
    u16* dst = Vt + nh * 128 * 512;
#pragma unroll
    for (int mt = 0; mt < 4; ++mt)
#pragma unroll
      for (int nc = 0; nc < 4; ++nc) {
        int col = cbase + nc * 16 + lr;
        int jb = jt * 64 + mt * 16 + lg * 4;
        u16x4 pk = {f2bf(acc[mt][nc][0]), f2bf(acc[mt][nc][1]),
                    f2bf(acc[mt][nc][2]), f2bf(acc[mt][nc][3])};
        *(u16x4*)&dst[(size_t)col * 512 + jb] = pk;
      }
  }
}

// ---------------- flash attention: LDS-staged K/V, in-register softmax ----
// Grid: 512 blocks 1D, remapped so the 4 qt-blocks of one (n,h) share an XCD.
// 256 threads (4 waves); wave owns 32 q-rows via swapped 32x32 MFMA.
// K tile [64][128] and Vt tile [128][64] staged with global_load_lds w=16,
// double-buffered; source-side XOR swizzle, same XOR on ds_read (rule #21).
__global__ __launch_bounds__(256, 2) void attn_kernel(
    const u16* __restrict__ Q, const u16* __restrict__ K,
    const u16* __restrict__ Vt, u16* __restrict__ O) {
  __shared__ u16 KL[2][64 * 128];
  __shared__ u16 VL[2][128 * 64];
  // XCD-friendly remap: xcd = flat&7 constant across qt for fixed (n,h)
  int flat = blockIdx.x;
  int xcd = flat & 7, idx = flat >> 3;
  int gl = idx & 15, qt = idx >> 4;        // qt 0..3
  int g = xcd | (gl << 3);                  // 0..127
  int h = g & 15, n = g >> 4;
  int tid = threadIdx.x, wv = tid >> 6, ln = tid & 63;
  int l31 = ln & 31, hh = ln >> 5;
  size_t nh = (size_t)(n * 16 + h);
  int q0 = qt * 128 + wv * 32;
  const u16* Qb = Q + ((size_t)nh * 512 + q0) * 128;
  const u16* Kb = K + (size_t)nh * 512 * 128;
  const u16* Vb = Vt + (size_t)nh * 128 * 512;

  bf16x8 qf[8];
#pragma unroll
  for (int kt = 0; kt < 8; ++kt)
    qf[kt] = ld16(&Qb[l31 * 128 + kt * 16 + hh * 8]);

  // staging lane geometry (per wave: 4 K-instrs + 4 V-instrs per tile)
  int l16 = ln & 15, l8 = ln & 7;
  int rK[4], cK[4], rV[4], cV[4];
#pragma unroll
  for (int i = 0; i < 4; ++i) {
    int s = wv * 4 + i;
    rK[i] = 4 * s + (ln >> 4);              // K tile row 0..63
    cK[i] = (l16 ^ (rK[i] & 15)) * 8;       // pre-swizzled source col
    rV[i] = 8 * s + (ln >> 3);              // V tile row (=d) 0..127
    cV[i] = (l8 ^ (rV[i] & 7)) * 8;
  }

  // prologue: stage tile 0
#pragma unroll
  for (int i = 0; i < 4; ++i) {
    int s = wv * 4 + i;
    gl_lds(&Kb[(size_t)rK[i] * 128 + cK[i]], &KL[0][s * 512]);
    gl_lds(&Vb[(size_t)rV[i] * 512 + 0 * 64 + cV[i]], &VL[0][s * 512]);
  }
  __syncthreads();

  f32x16 o[4] = {};
  float m = -1e30f, l = 0.f;

  for (int kv = 0; kv < 8; ++kv) {
    int cur = kv & 1;
    // stage next tile first (loads stay in flight under this tile's compute)
    if (kv < 7) {
      int nxt = cur ^ 1;
      const u16* kp = Kb + (size_t)(kv + 1) * 64 * 128;
#pragma unroll
      for (int i = 0; i < 4; ++i) {
        int s = wv * 4 + i;
        gl_lds(&kp[(size_t)rK[i] * 128 + cK[i]], &KL[nxt][s * 512]);
        gl_lds(&Vb[(size_t)rV[i] * 512 + (kv + 1) * 64 + cV[i]], &VL[nxt][s * 512]);
      }
    }
    // S^T = K Q^T : lane holds S[q=l31][k = 32*kb + (r&3)+8*(r>>2)+4*hh]
    f32x16 s[2] = {};
#pragma unroll
    for (int kb = 0; kb < 2; ++kb)
#pragma unroll
      for (int kt = 0; kt < 8; ++kt) {
        int row = kb * 32 + l31;
        int slot = (2 * kt + hh) ^ (row & 15);
        bf16x8 a = ld16(&KL[cur][row * 128 + slot * 8]);
        s[kb] = MFMA32(a, qf[kt], s[kb]);
      }
    // row max: in-lane tree + one cross-half shfl
    float mx[8];
#pragma unroll
    for (int i = 0; i < 8; ++i)
      mx[i] = fmaxf(fmaxf(s[0][2 * i], s[0][2 * i + 1]),
                    fmaxf(s[1][2 * i], s[1][2 * i + 1]));
    float pm = fmaxf(fmaxf(fmaxf(mx[0], mx[1]), fmaxf(mx[2], mx[3])),
                     fmaxf(fmaxf(mx[4], mx[5]), fmaxf(mx[6], mx[7])));
    pm = fmaxf(pm, __shfl_xor(pm, 32));
    // defer-max (T13): rescale only when running max grows by >8
    if (!__all(pm <= m + 8.f)) {
      float nm = fmaxf(m, pm);
      float al = __expf(m - nm);
      l *= al;
      m = nm;
#pragma unroll
      for (int r = 0; r < 16; ++r) {
        int qr = (r & 3) + 8 * (r >> 2) + 4 * hh;
        float av = __shfl(al, (ln & 32) | qr, 64);
        o[0][r] *= av; o[1][r] *= av; o[2][r] *= av; o[3][r] *= av;
      }
    }
    // exp + row sum
#pragma unroll
    for (int kb = 0; kb < 2; ++kb)
#pragma unroll
      for (int r = 0; r < 16; ++r) s[kb][r] = __expf(s[kb][r] - m);
    float sm[8];
#pragma unroll
    for (int i = 0; i < 8; ++i)
      sm[i] = (s[0][2 * i] + s[0][2 * i + 1]) + (s[1][2 * i] + s[1][2 * i + 1]);
    float rs = ((sm[0] + sm[1]) + (sm[2] + sm[3])) +
               ((sm[4] + sm[5]) + (sm[6] + sm[7]));
    rs += __shfl_xor(rs, 32);
    l += rs;
    // P -> PV A-frags in-register (T12: cvt_pk + permlane32_swap)
    bf16x8 pa[4];
#pragma unroll
    for (int ks = 0; ks < 4; ++ks) {
      const int kb = ks >> 1, r0 = 8 * (ks & 1);
      u32 wA, wB, wC, wD;
      asm("v_cvt_pk_bf16_f32 %0, %1, %2" : "=v"(wA) : "v"(s[kb][r0 + 0]), "v"(s[kb][r0 + 1]));
      asm("v_cvt_pk_bf16_f32 %0, %1, %2" : "=v"(wB) : "v"(s[kb][r0 + 2]), "v"(s[kb][r0 + 3]));
      asm("v_cvt_pk_bf16_f32 %0, %1, %2" : "=v"(wC) : "v"(s[kb][r0 + 4]), "v"(s[kb][r0 + 5]));
      asm("v_cvt_pk_bf16_f32 %0, %1, %2" : "=v"(wD) : "v"(s[kb][r0 + 6]), "v"(s[kb][r0 + 7]));
      asm("v_permlane32_swap_b32 %0, %1" : "+v"(wA), "+v"(wC));
      asm("v_permlane32_swap_b32 %0, %1" : "+v"(wB), "+v"(wD));
      uint4 ww = {wA, wB, wC, wD};
      pa[ks] = __builtin_bit_cast(bf16x8, ww);
    }
    // O += P V  (B[k][d] = VL[d][k], swizzled read)
#pragma unroll
    for (int ks = 0; ks < 4; ++ks)
#pragma unroll
      for (int nb = 0; nb < 4; ++nb) {
        int row = nb * 32 + l31;
        int slot = (2 * ks + hh) ^ (row & 7);
        bf16x8 bv = ld16(&VL[cur][row * 64 + slot * 8]);
        o[nb] = MFMA32(pa[ks], bv, o[nb]);
      }
    if (kv < 7) __syncthreads();  // drains staged loads; frees buf for kv+2
  }
  // normalize + write attn_out [n*512+q][2048]
  float inv = 1.f / l;
#pragma unroll
  for (int r = 0; r < 16; ++r) {
    int qr = (r & 3) + 8 * (r >> 2) + 4 * hh;
    float iv = __shfl(inv, (ln & 32) | qr, 64);
    int row = q0 + qr;
    u16* dst = O + ((size_t)n * 512 + row) * 2048 + h * 128;
    dst[0 * 32 + l31] = f2bf(o[0][r] * iv);
    dst[1 * 32 + l31] = f2bf(o[1][r] * iv);
    dst[2 * 32 + l31] = f2bf(o[2][r] * iv);
    dst[3 * 32 + l31] = f2bf(o[3][r] * iv);
  }
}

// ---------------- FC GEMM + bias + permuted scatter ----------------
__global__ __launch_bounds__(256) void fc_kernel(
    const u16* __restrict__ A, const u16* __restrict__ Bw,
    const float* __restrict__ bias, float* __restrict__ dout, int bsh) {
  __shared__ u16 Al[128 * 32];
  __shared__ u16 Bl[128 * 32];
  int bn = blockIdx.x, bm = blockIdx.y;
  int tid = threadIdx.x, wv = tid >> 6, ln = tid & 63;
  int lr = ln & 15, lg = ln >> 4;
  int R0 = bm * 128, C0 = bn * 128;
  int wr = (wv & 1) * 64, wc = (wv >> 1) * 64;
  int lrow = ln >> 2, lseg = ln & 3;
  f32x4 acc[4][4] = {};
  for (int ks = 0; ks < 64; ++ks) {
    int k0 = ks * 32;
#pragma unroll
    for (int ch = wv; ch < 8; ch += 4) {
      const u16* ga = A + (size_t)(R0 + ch * 16 + lrow) * 2048 + k0 + lseg * 8;
      gl_lds(ga, &Al[ch * 512]);
      const u16* gb = Bw + (size_t)(C0 + ch * 16 + lrow) * 2048 + k0 + lseg * 8;
      gl_lds(gb, &Bl[ch * 512]);
    }
    __syncthreads();
    bf16x8 a[4], b[4];
#pragma unroll
    for (int mt = 0; mt < 4; ++mt)
      a[mt] = ld16(&Al[(wr + mt * 16 + lr) * 32 + lg * 8]);
#pragma unroll
    for (int nc = 0; nc < 4; ++nc)
      b[nc] = ld16(&Bl[(wc + nc * 16 + lr) * 32 + lg * 8]);
#pragma unroll
    for (int mt = 0; mt < 4; ++mt)
#pragma unroll
      for (int nc = 0; nc < 4; ++nc)
        acc[mt][nc] = MFMA16(a[mt], b[nc], acc[mt][nc]);
    __syncthreads();
  }
#pragma unroll
  for (int nc = 0; nc < 4; ++nc) {
    int e = C0 + wc + nc * 16 + lr;
    float bv = bias[e];
    int i = e >> 8, cc = e & 255;
#pragma unroll
    for (int mt = 0; mt < 4; ++mt)
#pragma unroll
      for (int r = 0; r < 4; ++r) {
        int row = R0 + wr + mt * 16 + lg * 4 + r;
        int nn = row >> 9, j = row & 511;
        int pos = (8 * j + i - bsh) & 4095;
        dout[((size_t)nn * 4096 + pos) * 256 + cc] = acc[mt][nc][r] + bv;
      }
  }
}

extern "C" void kernel_launch(void* const* d_in, const int* in_sizes, int n_in,
                              void* d_out, int out_size, void* d_ws, size_t ws_size,
                              hipStream_t stream) {
  const float* M = (const float*)d_in[0];
  const float* Wq = (const float*)d_in[1];
  const float* Wk = (const float*)d_in[2];
  const float* Wv = (const float*)d_in[3];
  const float* fcw = (const float*)d_in[4];
  const float* fcb = (const float*)d_in[5];
  float* out = (float*)d_out;
  char* ws = (char*)d_ws;
  u16* wq_b = (u16*)(ws + (0 << 10));
  u16* wk_b = (u16*)(ws + (32 << 10));
  u16* wv_b = (u16*)(ws + (64 << 10));
  u16* fcw_b = (u16*)(ws + (128 << 10));
  u16* Qb = (u16*)(ws + ((size_t)16 << 20));
  u16* Kb = (u16*)(ws + ((size_t)32 << 20));
  u16* Vtb = (u16*)(ws + ((size_t)48 << 20));
  u16* Ab = (u16*)(ws + ((size_t)64 << 20));

  convert_weights<<<4112, 256, 0, stream>>>(Wq, Wk, Wv, fcw, wq_b, wk_b, wv_b, fcw_b);
  for (int b = 0; b < 8; ++b) {
    const float* src = (b == 0) ? M : out;
    qkv_kernel<<<dim3(8, 16, 8), 384, 0, stream>>>(src, wq_b, wk_b, wv_b, Qb, Kb, Vtb, b);
    attn_kernel<<<512, 256, 0, stream>>>(Qb, Kb, Vtb, Ab);
    fc_kernel<<<dim3(16, 32), 256, 0, stream>>>(Ab, fcw_b, fcb, out, b);
  }
}